// Round 6
// baseline (93.609 us; speedup 1.0000x reference)
//
#include <hip/hip_runtime.h>

// Bottom-up HTMM upward pass.
// Key idea this round: the leaf level is a pure function of (pos l, symbol m,
// g), so its entire contribution to the mid-level contraction is tabulated:
//   T[l][m][g][i]  = sum_j smPi[j,l,g] smB[j,m,g] M[l,j,i,g] / nu(l,m,g)
//   ltab[l][m][g]  = log nu(l,m,g),  nu = sum_c smPi[c,l,g] smB[c,m,g]
// Leaf+transition per mid-parent then = 8 table gathers + 64 adds (was 512 FMA).
// Waves stay g-uniform so the inner-level kernels stream M via scalar loads.
// Tree structure implicit: starts[d]=(8^d-1)/7, child position == local%8.

constexpr int NT_NODES = 299593;
constexpr int S0 = 0, S1 = 1, S2 = 9, S3 = 73, S4 = 585, S5 = 4681, S6 = 37449;

// ---------------- stage0T: one block per g — softmaxes + T/ltab ----------------
// Tables:
//   MtN   [g][l][j][i] : 8192   (= smSP[l,g]*smA[i,j,l,g])
//   Mt_old[g][j][l][i] : 8192   (tail kernel layout)
//   smBtN [g][m][c]    : 4096
//   smBt_old[m][g][c]  : 4096   (tail layout)
//   Tt    [l][m][g][i] : 32768
//   ltab  [l][m][g]    : 4096
__global__ __launch_bounds__(256) void stage0T(
    const float* __restrict__ A, const float* __restrict__ B,
    const float* __restrict__ Pi, const float* __restrict__ SP,
    float* __restrict__ Mt_old, float* __restrict__ MtN,
    float* __restrict__ smBt_old, float* __restrict__ smBtN,
    float* __restrict__ Tt, float* __restrict__ ltab)
{
    int g = blockIdx.x;
    int tid = threadIdx.x;
    __shared__ __align__(16) float mL[512];   // [l][j][i] = M (with smSP folded)
    __shared__ __align__(16) float bLs[256];  // [m][c]
    __shared__ __align__(16) float piLs[64];  // [l][c]

    // smSP for this g (computed redundantly per thread; broadcast loads)
    float sp[8];
    {
        float mx = -1e30f;
        #pragma unroll
        for (int l = 0; l < 8; ++l) { sp[l] = SP[l * 16 + g]; mx = fmaxf(mx, sp[l]); }
        float s = 0.f;
        #pragma unroll
        for (int l = 0; l < 8; ++l) { sp[l] = __expf(sp[l] - mx); s += sp[l]; }
        float r = 1.f / s;
        #pragma unroll
        for (int l = 0; l < 8; ++l) sp[l] *= r;
    }

    if (tid < 64) {
        // A-softmax over i for (j,l)
        int j = tid & 7, l = tid >> 3;
        float a[8]; float mx = -1e30f;
        #pragma unroll
        for (int i = 0; i < 8; ++i) { a[i] = A[((i * 8 + j) * 8 + l) * 16 + g]; mx = fmaxf(mx, a[i]); }
        float s = 0.f;
        #pragma unroll
        for (int i = 0; i < 8; ++i) { a[i] = __expf(a[i] - mx); s += a[i]; }
        float scale = sp[l] / s;
        #pragma unroll
        for (int i = 0; i < 8; ++i) {
            float m = a[i] * scale;
            mL[(l * 8 + j) * 8 + i] = m;
            MtN[((g * 8 + l) * 8 + j) * 8 + i] = m;
            Mt_old[((g * 8 + j) * 8 + l) * 8 + i] = m;
        }
    } else if (tid < 72) {
        // B-softmax over m for state c
        int c = tid - 64;
        float vv[32]; float mx = -1e30f;
        #pragma unroll
        for (int m = 0; m < 32; ++m) { vv[m] = B[(c * 32 + m) * 16 + g]; mx = fmaxf(mx, vv[m]); }
        float s = 0.f;
        #pragma unroll
        for (int m = 0; m < 32; ++m) { vv[m] = __expf(vv[m] - mx); s += vv[m]; }
        float r = 1.f / s;
        #pragma unroll
        for (int m = 0; m < 32; ++m) {
            float p = vv[m] * r;
            bLs[m * 8 + c] = p;
            smBt_old[(m * 16 + g) * 8 + c] = p;
            smBtN[(g * 32 + m) * 8 + c] = p;
        }
    } else if (tid < 80) {
        // Pi-softmax over c for position l
        int l = tid - 72;
        float a[8]; float mx = -1e30f;
        #pragma unroll
        for (int c = 0; c < 8; ++c) { a[c] = Pi[(c * 8 + l) * 16 + g]; mx = fmaxf(mx, a[c]); }
        float s = 0.f;
        #pragma unroll
        for (int c = 0; c < 8; ++c) { a[c] = __expf(a[c] - mx); s += a[c]; }
        float r = 1.f / s;
        #pragma unroll
        for (int c = 0; c < 8; ++c) piLs[l * 8 + c] = a[c] * r;
    }
    __syncthreads();

    // per (l,m): nu, ltab, T row
    {
        int m = tid & 31, l = tid >> 5;
        float pb[8]; float w = 0.f;
        #pragma unroll
        for (int c = 0; c < 8; ++c) { pb[c] = piLs[l * 8 + c] * bLs[m * 8 + c]; w += pb[c]; }
        ltab[(l * 32 + m) * 16 + g] = __logf(w);
        float rw = 1.f / w;
        float t[8];
        #pragma unroll
        for (int i = 0; i < 8; ++i) t[i] = 0.f;
        #pragma unroll
        for (int c = 0; c < 8; ++c) {
            float p = pb[c];
            #pragma unroll
            for (int i = 0; i < 8; ++i) t[i] = fmaf(p, mL[(l * 8 + c) * 8 + i], t[i]);
        }
        float* dst = Tt + ((l * 32 + m) * 16 + g) * 8;
        #pragma unroll
        for (int i = 0; i < 8; ++i) dst[i] = t[i] * rw;
    }
}

// ---------------- leaf upsweep: levels 6 -> 5 -> 4 via T table ----------------
// Block = 256 thr = 4 waves; wave = one g (g = gq*4+wave), thread = one
// level-5 mid-parent. grid.x = 1024*4.
__global__ __launch_bounds__(256) void upleaf(
    const float* __restrict__ MtN, const float* __restrict__ smBtN,
    const float* __restrict__ Tt, const float* __restrict__ ltab,
    const int* __restrict__ x,
    float* __restrict__ dstBeta,   // [g][8192][8]
    float* __restrict__ llout)     // [g][1024]
{
    constexpr int SPT = 4096;      // level-4 subtrees per tree
    int sg = blockIdx.x >> 2;
    int gq = blockIdx.x & 3;
    int wave = threadIdx.x >> 6;
    int lane = threadIdx.x & 63;
    int g = gq * 4 + wave;                        // wave-uniform
    int gu = __builtin_amdgcn_readfirstlane(g);
    int u = lane & 7;
    int s = sg * 8 + (lane >> 3);
    int t = (s >= SPT) ? 1 : 0;
    int localS = s - t * SPT;
    int localP = localS * 8 + u;
    const int base = t * NT_NODES;

    // leaves: pa[i] = sum_l T[l][x_l][g][i];  ll += sum_l ltab[l][x_l][g]
    int xl[8];
    {
        const int xb = base + S6 + localP * 8;
        #pragma unroll
        for (int l = 0; l < 8; ++l) xl[l] = x[xb + l];
    }
    float pa[8] = {0.f, 0.f, 0.f, 0.f, 0.f, 0.f, 0.f, 0.f};
    float ll = 0.f;
    #pragma unroll
    for (int l = 0; l < 8; ++l) {
        int row = (l * 32 + xl[l]) * 16 + g;
        const float4* tp = (const float4*)(Tt + row * 8);
        float4 t0 = tp[0], t1 = tp[1];
        pa[0] += t0.x; pa[1] += t0.y; pa[2] += t0.z; pa[3] += t0.w;
        pa[4] += t1.x; pa[5] += t1.y; pa[6] += t1.z; pa[7] += t1.w;
        ll += ltab[row];
    }

    // mid emission + normalize
    float bm[8];
    {
        int xm = x[base + S5 + localP];
        const float4* ep = (const float4*)(smBtN + ((gu << 5) + xm) * 8);
        float4 e0 = ep[0], e1 = ep[1];
        pa[0] *= e0.x; pa[1] *= e0.y; pa[2] *= e0.z; pa[3] *= e0.w;
        pa[4] *= e1.x; pa[5] *= e1.y; pa[6] *= e1.z; pa[7] *= e1.w;
        float nu = ((pa[0] + pa[1]) + (pa[2] + pa[3])) + ((pa[4] + pa[5]) + (pa[6] + pa[7]));
        ll += __logf(nu);
        float rn = __builtin_amdgcn_rcpf(nu);
        #pragma unroll
        for (int c = 0; c < 8; ++c) bm[c] = pa[c] * rn;
    }

    // root: lane's partial over its own child-position u, butterfly over octet
    {
        float pr[8] = {0.f, 0.f, 0.f, 0.f, 0.f, 0.f, 0.f, 0.f};
        const float4* mr = (const float4*)(MtN + (gu << 9) + (u << 6));
        #pragma unroll
        for (int j = 0; j < 8; ++j) {
            float4 m0 = mr[j * 2], m1 = mr[j * 2 + 1];
            float b = bm[j];
            pr[0] = fmaf(b, m0.x, pr[0]); pr[1] = fmaf(b, m0.y, pr[1]);
            pr[2] = fmaf(b, m0.z, pr[2]); pr[3] = fmaf(b, m0.w, pr[3]);
            pr[4] = fmaf(b, m1.x, pr[4]); pr[5] = fmaf(b, m1.y, pr[5]);
            pr[6] = fmaf(b, m1.z, pr[6]); pr[7] = fmaf(b, m1.w, pr[7]);
        }
        #pragma unroll
        for (int m = 1; m <= 4; m <<= 1) {
            #pragma unroll
            for (int i = 0; i < 8; ++i) pr[i] += __shfl_xor(pr[i], m);
        }
        int xr = x[base + S4 + localS];
        const float4* ep = (const float4*)(smBtN + ((gu << 5) + xr) * 8);
        float4 e0 = ep[0], e1 = ep[1];
        pr[0] *= e0.x; pr[1] *= e0.y; pr[2] *= e0.z; pr[3] *= e0.w;
        pr[4] *= e1.x; pr[5] *= e1.y; pr[6] *= e1.z; pr[7] *= e1.w;
        float nur = ((pr[0] + pr[1]) + (pr[2] + pr[3])) + ((pr[4] + pr[5]) + (pr[6] + pr[7]));
        float rr = __builtin_amdgcn_rcpf(nur);
        if (u == 0) {
            ll += __logf(nur);
            float4* dp = (float4*)(dstBeta + ((size_t)g * 8192 + s) * 8);
            dp[0] = make_float4(pr[0] * rr, pr[1] * rr, pr[2] * rr, pr[3] * rr);
            dp[1] = make_float4(pr[4] * rr, pr[5] * rr, pr[6] * rr, pr[7] * rr);
        }
    }

    #pragma unroll
    for (int m = 1; m < 64; m <<= 1) ll += __shfl_xor(ll, m);
    if (lane == 0) llout[g * 1024 + sg] = ll;
}

// ---------------- inner upsweep: two levels, scalar-M sweep (round-5) ----------------
template <int NSG, int SMID, int SROOT, int SRC_PT, int NSRC_TOT, int NDST_TOT>
__global__ __launch_bounds__(256) void up2(
    const float* __restrict__ MtN, const float* __restrict__ smBtN,
    const int* __restrict__ x,
    const float* __restrict__ srcBeta,   // [g][NSRC_TOT][8]
    float* __restrict__ dstBeta,         // [g][NDST_TOT][8]
    float* __restrict__ llout,           // [g][NSG]
    const float* __restrict__ llin, int llstride)
{
    constexpr int SPT = NSG * 4;
    int sg = blockIdx.x >> 2;
    int gq = blockIdx.x & 3;
    int wave = threadIdx.x >> 6;
    int lane = threadIdx.x & 63;
    int g = gq * 4 + wave;
    int gu = __builtin_amdgcn_readfirstlane(g);
    int u = lane & 7;
    int s = sg * 8 + (lane >> 3);
    int t = (s >= SPT) ? 1 : 0;
    int localS = s - t * SPT;
    int localP = localS * 8 + u;
    const int base = t * NT_NODES;

    float ll = 0.f;
    float bch[64];
    {
        const float4* sp = (const float4*)(srcBeta +
            ((size_t)g * NSRC_TOT + (size_t)t * SRC_PT + (size_t)localP * 8) * 8);
        #pragma unroll
        for (int v = 0; v < 16; ++v) {
            float4 f = sp[v];
            bch[4 * v + 0] = f.x; bch[4 * v + 1] = f.y;
            bch[4 * v + 2] = f.z; bch[4 * v + 3] = f.w;
        }
    }

    float pa[8] = {0.f, 0.f, 0.f, 0.f, 0.f, 0.f, 0.f, 0.f};
    const float* Mg = MtN + (gu << 9);
    #pragma unroll
    for (int k = 0; k < 64; ++k) {
        float b = bch[k];
        #pragma unroll
        for (int i = 0; i < 8; ++i) pa[i] = fmaf(b, Mg[k * 8 + i], pa[i]);
    }

    float bm[8];
    {
        int xm = x[base + SMID + localP];
        const float4* ep = (const float4*)(smBtN + ((gu << 5) + xm) * 8);
        float4 e0 = ep[0], e1 = ep[1];
        pa[0] *= e0.x; pa[1] *= e0.y; pa[2] *= e0.z; pa[3] *= e0.w;
        pa[4] *= e1.x; pa[5] *= e1.y; pa[6] *= e1.z; pa[7] *= e1.w;
        float nu = ((pa[0] + pa[1]) + (pa[2] + pa[3])) + ((pa[4] + pa[5]) + (pa[6] + pa[7]));
        ll += __logf(nu);
        float rn = __builtin_amdgcn_rcpf(nu);
        #pragma unroll
        for (int c = 0; c < 8; ++c) bm[c] = pa[c] * rn;
    }

    {
        float pr[8] = {0.f, 0.f, 0.f, 0.f, 0.f, 0.f, 0.f, 0.f};
        const float4* mr = (const float4*)(MtN + (gu << 9) + (u << 6));
        #pragma unroll
        for (int j = 0; j < 8; ++j) {
            float4 m0 = mr[j * 2], m1 = mr[j * 2 + 1];
            float b = bm[j];
            pr[0] = fmaf(b, m0.x, pr[0]); pr[1] = fmaf(b, m0.y, pr[1]);
            pr[2] = fmaf(b, m0.z, pr[2]); pr[3] = fmaf(b, m0.w, pr[3]);
            pr[4] = fmaf(b, m1.x, pr[4]); pr[5] = fmaf(b, m1.y, pr[5]);
            pr[6] = fmaf(b, m1.z, pr[6]); pr[7] = fmaf(b, m1.w, pr[7]);
        }
        #pragma unroll
        for (int m = 1; m <= 4; m <<= 1) {
            #pragma unroll
            for (int i = 0; i < 8; ++i) pr[i] += __shfl_xor(pr[i], m);
        }
        int xr = x[base + SROOT + localS];
        const float4* ep = (const float4*)(smBtN + ((gu << 5) + xr) * 8);
        float4 e0 = ep[0], e1 = ep[1];
        pr[0] *= e0.x; pr[1] *= e0.y; pr[2] *= e0.z; pr[3] *= e0.w;
        pr[4] *= e1.x; pr[5] *= e1.y; pr[6] *= e1.z; pr[7] *= e1.w;
        float nur = ((pr[0] + pr[1]) + (pr[2] + pr[3])) + ((pr[4] + pr[5]) + (pr[6] + pr[7]));
        float rr = __builtin_amdgcn_rcpf(nur);
        if (u == 0) {
            ll += __logf(nur);
            float4* dp = (float4*)(dstBeta + ((size_t)g * NDST_TOT + s) * 8);
            dp[0] = make_float4(pr[0] * rr, pr[1] * rr, pr[2] * rr, pr[3] * rr);
            dp[1] = make_float4(pr[4] * rr, pr[5] * rr, pr[6] * rr, pr[7] * rr);
        }
    }

    if (llin) ll += llin[g * llstride + sg * 64 + lane];
    #pragma unroll
    for (int m = 1; m < 64; m <<= 1) ll += __shfl_xor(ll, m);
    if (lane == 0) llout[g * NSG + sg] = ll;
}

// static 1-of-8 select by lane bits (7 cndmask)
__device__ __forceinline__ float sel8(const float v[8], bool c0, bool c1, bool c2) {
    float a0 = c0 ? v[1] : v[0];
    float a1 = c0 ? v[3] : v[2];
    float a2 = c0 ? v[5] : v[4];
    float a3 = c0 ? v[7] : v[6];
    float b0 = c1 ? a1 : a0;
    float b1 = c1 ? a3 : a2;
    return c2 ? b1 : b0;
}

// ---------------- tail: levels 2 -> 1 -> 0, one block per tree ----------------
__global__ __launch_bounds__(128) void tail(
    const float* __restrict__ Mt_old, const float* __restrict__ smBt_old,
    const int* __restrict__ x, const float* __restrict__ src /* [g][128][8] */,
    float* __restrict__ out, const float* __restrict__ ll2 /* [g][16] */)
{
    int b = blockIdx.x;
    int tid = threadIdx.x;
    int g = tid >> 3, j = tid & 7;
    bool c0 = (j & 1) != 0, c1 = (j & 2) != 0, c2 = (j & 4) != 0;
    const int nodebase = b * NT_NODES;

    float ll_priv = ll2[g * 16 + b * 8 + j];

    float M[64];
    {
        const float4* mp = (const float4*)(Mt_old + tid * 64);
        #pragma unroll
        for (int v = 0; v < 16; ++v) {
            float4 f = mp[v];
            M[4 * v + 0] = f.x; M[4 * v + 1] = f.y;
            M[4 * v + 2] = f.z; M[4 * v + 3] = f.w;
        }
    }

    int xm = x[nodebase + S1 + j];
    float ll = 0.f;
    float bmid[8];
    const float* sb = src + g * 1024 + b * 512 + j;

    #pragma unroll
    for (int u = 0; u < 8; ++u) {
        float bch[8];
        #pragma unroll
        for (int l = 0; l < 8; ++l) bch[l] = sb[(u * 8 + l) * 8];
        float pa[8];
        #pragma unroll
        for (int i = 0; i < 8; ++i) {
            float s = bch[0] * M[0 * 8 + i];
            #pragma unroll
            for (int l = 1; l < 8; ++l) s = fmaf(bch[l], M[l * 8 + i], s);
            pa[i] = s;
        }
        #pragma unroll
        for (int m = 1; m <= 4; m <<= 1) {
            #pragma unroll
            for (int i = 0; i < 8; ++i) pa[i] += __shfl_xor(pa[i], m);
        }
        int xv = __shfl(xm, u);
        const float4* bp = (const float4*)(smBt_old + xv * 128 + g * 8);
        float4 b0 = bp[0], b1 = bp[1];
        pa[0] *= b0.x; pa[1] *= b0.y; pa[2] *= b0.z; pa[3] *= b0.w;
        pa[4] *= b1.x; pa[5] *= b1.y; pa[6] *= b1.z; pa[7] *= b1.w;
        float nu = ((pa[0] + pa[1]) + (pa[2] + pa[3])) + ((pa[4] + pa[5]) + (pa[6] + pa[7]));
        ll += __logf(nu);
        bmid[u] = sel8(pa, c0, c1, c2) * __builtin_amdgcn_rcpf(nu);
    }

    {
        float pa[8];
        #pragma unroll
        for (int i = 0; i < 8; ++i) {
            float s = bmid[0] * M[0 * 8 + i];
            #pragma unroll
            for (int l = 1; l < 8; ++l) s = fmaf(bmid[l], M[l * 8 + i], s);
            pa[i] = s;
        }
        #pragma unroll
        for (int m = 1; m <= 4; m <<= 1) {
            #pragma unroll
            for (int i = 0; i < 8; ++i) pa[i] += __shfl_xor(pa[i], m);
        }
        int xv = x[nodebase + S0];
        const float4* bp = (const float4*)(smBt_old + xv * 128 + g * 8);
        float4 b0 = bp[0], b1 = bp[1];
        pa[0] *= b0.x; pa[1] *= b0.y; pa[2] *= b0.z; pa[3] *= b0.w;
        pa[4] *= b1.x; pa[5] *= b1.y; pa[6] *= b1.z; pa[7] *= b1.w;
        float nu = ((pa[0] + pa[1]) + (pa[2] + pa[3])) + ((pa[4] + pa[5]) + (pa[6] + pa[7]));
        ll += __logf(nu);
    }

    float s = ll_priv;
    s += __shfl_xor(s, 1); s += __shfl_xor(s, 2); s += __shfl_xor(s, 4);
    if (j == 0) out[b * 16 + g] = s + ll;
}

extern "C" void kernel_launch(void* const* d_in, const int* in_sizes, int n_in,
                              void* d_out, int out_size, void* d_ws, size_t ws_size,
                              hipStream_t stream)
{
    const float* A  = (const float*)d_in[0];
    const float* B  = (const float*)d_in[1];
    const float* Pi = (const float*)d_in[2];
    const float* SP = (const float*)d_in[3];
    const int*   x  = (const int*)d_in[4];

    float* ws      = (float*)d_ws;
    float* Mt_old  = ws;                      // 8192
    float* MtN     = Mt_old + 8192;           // 8192
    float* smBt_o  = MtN + 8192;              // 4096
    float* smBtN   = smBt_o + 4096;           // 4096
    float* Tt      = smBtN + 4096;            // 32768
    float* ltab    = Tt + 32768;              // 4096
    float* lv4     = ltab + 4096;             // 16*8192*8 = 1048576
    float* lv2     = lv4 + 1048576;           // 16*128*8  = 16384
    float* ll1     = lv2 + 16384;             // 16*1024   = 16384
    float* ll2     = ll1 + 16384;             // 16*16     = 256
    float* out     = (float*)d_out;

    stage0T<<<16, 256, 0, stream>>>(A, B, Pi, SP, Mt_old, MtN, smBt_o, smBtN, Tt, ltab);
    // levels 6 -> 5 -> 4 via T table
    upleaf<<<4096, 256, 0, stream>>>(MtN, smBtN, Tt, ltab, x, lv4, ll1);
    // levels 4 -> 3 -> 2 (+ fold ll1)
    up2<16, S3, S2, 4096, 8192, 128><<<64, 256, 0, stream>>>(
        MtN, smBtN, x, lv4, lv2, ll2, ll1, 1024);
    // levels 2 -> 1 -> 0 (+ fold ll2), writes out[2][16]
    tail<<<2, 128, 0, stream>>>(Mt_old, smBt_o, x, lv2, out, ll2);
}

// Round 7
// 64.717 us; speedup vs baseline: 1.4464x; 1.4464x over previous
//
#include <hip/hip_runtime.h>

// Bottom-up HTMM upward pass.
// Round-7 change: the leaf kernel's data-dependent table lookups (T, ltab,
// smB rows keyed by symbol) move from divergent GLOBAL gathers (TA-bound,
// ~50+cyc each) into LDS with a 9-float row stride. gcd(9,32)=1 makes the
// symbol->bank map bijective, so divergent reads are conflict-free.
// Tree structure implicit: starts[d]=(8^d-1)/7, child position == local%8.

constexpr int NT_NODES = 299593;
constexpr int S0 = 0, S1 = 1, S2 = 9, S3 = 73, S4 = 585, S5 = 4681, S6 = 37449;

// ---------------- stage0T: one block per g — softmaxes + T/ltab ----------------
// Tables:
//   MtN   [g][l][j][i] : 8192   (= smSP[l,g]*smA[i,j,l,g])
//   Mt_old[g][j][l][i] : 8192   (tail kernel layout)
//   smBtN [g][m][c]    : 4096
//   smBt_old[m][g][c]  : 4096   (tail layout)
//   Tt    [l][m][g][i] : 32768
//   ltab  [l][m][g]    : 4096
__global__ __launch_bounds__(256) void stage0T(
    const float* __restrict__ A, const float* __restrict__ B,
    const float* __restrict__ Pi, const float* __restrict__ SP,
    float* __restrict__ Mt_old, float* __restrict__ MtN,
    float* __restrict__ smBt_old, float* __restrict__ smBtN,
    float* __restrict__ Tt, float* __restrict__ ltab)
{
    int g = blockIdx.x;
    int tid = threadIdx.x;
    __shared__ __align__(16) float mL[512];   // [l][j][i] = M (with smSP folded)
    __shared__ __align__(16) float bLs[256];  // [m][c]
    __shared__ __align__(16) float piLs[64];  // [l][c]

    // smSP for this g (computed redundantly per thread; broadcast loads)
    float sp[8];
    {
        float mx = -1e30f;
        #pragma unroll
        for (int l = 0; l < 8; ++l) { sp[l] = SP[l * 16 + g]; mx = fmaxf(mx, sp[l]); }
        float s = 0.f;
        #pragma unroll
        for (int l = 0; l < 8; ++l) { sp[l] = __expf(sp[l] - mx); s += sp[l]; }
        float r = 1.f / s;
        #pragma unroll
        for (int l = 0; l < 8; ++l) sp[l] *= r;
    }

    if (tid < 64) {
        // A-softmax over i for (j,l)
        int j = tid & 7, l = tid >> 3;
        float a[8]; float mx = -1e30f;
        #pragma unroll
        for (int i = 0; i < 8; ++i) { a[i] = A[((i * 8 + j) * 8 + l) * 16 + g]; mx = fmaxf(mx, a[i]); }
        float s = 0.f;
        #pragma unroll
        for (int i = 0; i < 8; ++i) { a[i] = __expf(a[i] - mx); s += a[i]; }
        float scale = sp[l] / s;
        #pragma unroll
        for (int i = 0; i < 8; ++i) {
            float m = a[i] * scale;
            mL[(l * 8 + j) * 8 + i] = m;
            MtN[((g * 8 + l) * 8 + j) * 8 + i] = m;
            Mt_old[((g * 8 + j) * 8 + l) * 8 + i] = m;
        }
    } else if (tid < 72) {
        // B-softmax over m for state c
        int c = tid - 64;
        float vv[32]; float mx = -1e30f;
        #pragma unroll
        for (int m = 0; m < 32; ++m) { vv[m] = B[(c * 32 + m) * 16 + g]; mx = fmaxf(mx, vv[m]); }
        float s = 0.f;
        #pragma unroll
        for (int m = 0; m < 32; ++m) { vv[m] = __expf(vv[m] - mx); s += vv[m]; }
        float r = 1.f / s;
        #pragma unroll
        for (int m = 0; m < 32; ++m) {
            float p = vv[m] * r;
            bLs[m * 8 + c] = p;
            smBt_old[(m * 16 + g) * 8 + c] = p;
            smBtN[(g * 32 + m) * 8 + c] = p;
        }
    } else if (tid < 80) {
        // Pi-softmax over c for position l
        int l = tid - 72;
        float a[8]; float mx = -1e30f;
        #pragma unroll
        for (int c = 0; c < 8; ++c) { a[c] = Pi[(c * 8 + l) * 16 + g]; mx = fmaxf(mx, a[c]); }
        float s = 0.f;
        #pragma unroll
        for (int c = 0; c < 8; ++c) { a[c] = __expf(a[c] - mx); s += a[c]; }
        float r = 1.f / s;
        #pragma unroll
        for (int c = 0; c < 8; ++c) piLs[l * 8 + c] = a[c] * r;
    }
    __syncthreads();

    // per (l,m): nu, ltab, T row
    {
        int m = tid & 31, l = tid >> 5;
        float pb[8]; float w = 0.f;
        #pragma unroll
        for (int c = 0; c < 8; ++c) { pb[c] = piLs[l * 8 + c] * bLs[m * 8 + c]; w += pb[c]; }
        ltab[(l * 32 + m) * 16 + g] = __logf(w);
        float rw = 1.f / w;
        float t[8];
        #pragma unroll
        for (int i = 0; i < 8; ++i) t[i] = 0.f;
        #pragma unroll
        for (int c = 0; c < 8; ++c) {
            float p = pb[c];
            #pragma unroll
            for (int i = 0; i < 8; ++i) t[i] = fmaf(p, mL[(l * 8 + c) * 8 + i], t[i]);
        }
        float* dst = Tt + ((l * 32 + m) * 16 + g) * 8;
        #pragma unroll
        for (int i = 0; i < 8; ++i) dst[i] = t[i] * rw;
    }
}

// ---------------- leaf upsweep: levels 6 -> 5 -> 4, LDS tables ----------------
// Block = 256 thr = 4 waves, ONE g per block (g = bid & 15); thread = one
// level-5 mid-parent. grid.x = 256 parent-groups * 16 g = 4096.
// LDS rows have stride 9 floats: bank(m) = (9m+i) mod 32 is a bijection over
// the 32 symbols -> divergent symbol-indexed reads are bank-conflict-free.
__global__ __launch_bounds__(256) void upleaf(
    const float* __restrict__ MtN, const float* __restrict__ smBtN,
    const float* __restrict__ Tt, const float* __restrict__ ltab,
    const int* __restrict__ x,
    float* __restrict__ dstBeta,   // [g][8192][8]
    float* __restrict__ llout)     // [g][1024]
{
    __shared__ float Tl[256 * 9 + 32 * 9];   // rows: T+ltab; then smBt rows

    int bid = blockIdx.x;
    int g = bid & 15;
    int pg = bid >> 4;                 // 0..255
    int tid = threadIdx.x;
    int wave = tid >> 6;
    int lane = tid & 63;
    int gu = __builtin_amdgcn_readfirstlane(g);
    int u = tid & 7;
    int s = pg * 32 + (tid >> 3);      // global level-4 subtree 0..8191
    int t = (s >= 4096) ? 1 : 0;
    int localS = s - t * 4096;
    int localP = localS * 8 + u;
    const int base = t * NT_NODES;

    // ---- fill LDS tables (one g) ----
    {
        // T row tid: 8 floats + ltab as 9th
        const float4* tp = (const float4*)(Tt + ((size_t)(tid * 16 + gu)) * 8);
        float4 t0 = tp[0], t1 = tp[1];
        float* dst = Tl + tid * 9;
        dst[0] = t0.x; dst[1] = t0.y; dst[2] = t0.z; dst[3] = t0.w;
        dst[4] = t1.x; dst[5] = t1.y; dst[6] = t1.z; dst[7] = t1.w;
        dst[8] = ltab[tid * 16 + gu];
        if (tid < 32) {
            const float4* bp = (const float4*)(smBtN + ((gu << 5) + tid) * 8);
            float4 b0 = bp[0], b1 = bp[1];
            float* d2 = Tl + 2304 + tid * 9;
            d2[0] = b0.x; d2[1] = b0.y; d2[2] = b0.z; d2[3] = b0.w;
            d2[4] = b1.x; d2[5] = b1.y; d2[6] = b1.z; d2[7] = b1.w;
        }
    }
    __syncthreads();

    // ---- leaves: pa[i] = sum_l T[l][x_l][i]; ll += sum_l ltab[l][x_l] ----
    int xl[8];
    {
        const int xb = base + S6 + localP * 8;
        #pragma unroll
        for (int l = 0; l < 8; ++l) xl[l] = x[xb + l];
    }
    float pa[8] = {0.f, 0.f, 0.f, 0.f, 0.f, 0.f, 0.f, 0.f};
    float ll = 0.f;
    #pragma unroll
    for (int l = 0; l < 8; ++l) {
        const float* row = Tl + (l * 32 + xl[l]) * 9;
        pa[0] += row[0]; pa[1] += row[1]; pa[2] += row[2]; pa[3] += row[3];
        pa[4] += row[4]; pa[5] += row[5]; pa[6] += row[6]; pa[7] += row[7];
        ll += row[8];
    }

    // ---- mid emission + normalize ----
    float bm[8];
    {
        int xm = x[base + S5 + localP];
        const float* er = Tl + 2304 + xm * 9;
        pa[0] *= er[0]; pa[1] *= er[1]; pa[2] *= er[2]; pa[3] *= er[3];
        pa[4] *= er[4]; pa[5] *= er[5]; pa[6] *= er[6]; pa[7] *= er[7];
        float nu = ((pa[0] + pa[1]) + (pa[2] + pa[3])) + ((pa[4] + pa[5]) + (pa[6] + pa[7]));
        ll += __logf(nu);
        float rn = __builtin_amdgcn_rcpf(nu);
        #pragma unroll
        for (int c = 0; c < 8; ++c) bm[c] = pa[c] * rn;
    }

    // ---- root: partial over own child-position u, butterfly over octet ----
    {
        float pr[8] = {0.f, 0.f, 0.f, 0.f, 0.f, 0.f, 0.f, 0.f};
        const float4* mr = (const float4*)(MtN + (gu << 9) + (u << 6));
        #pragma unroll
        for (int j = 0; j < 8; ++j) {
            float4 m0 = mr[j * 2], m1 = mr[j * 2 + 1];
            float b = bm[j];
            pr[0] = fmaf(b, m0.x, pr[0]); pr[1] = fmaf(b, m0.y, pr[1]);
            pr[2] = fmaf(b, m0.z, pr[2]); pr[3] = fmaf(b, m0.w, pr[3]);
            pr[4] = fmaf(b, m1.x, pr[4]); pr[5] = fmaf(b, m1.y, pr[5]);
            pr[6] = fmaf(b, m1.z, pr[6]); pr[7] = fmaf(b, m1.w, pr[7]);
        }
        #pragma unroll
        for (int m = 1; m <= 4; m <<= 1) {
            #pragma unroll
            for (int i = 0; i < 8; ++i) pr[i] += __shfl_xor(pr[i], m);
        }
        int xr = x[base + S4 + localS];
        const float* er = Tl + 2304 + xr * 9;
        pr[0] *= er[0]; pr[1] *= er[1]; pr[2] *= er[2]; pr[3] *= er[3];
        pr[4] *= er[4]; pr[5] *= er[5]; pr[6] *= er[6]; pr[7] *= er[7];
        float nur = ((pr[0] + pr[1]) + (pr[2] + pr[3])) + ((pr[4] + pr[5]) + (pr[6] + pr[7]));
        float rr = __builtin_amdgcn_rcpf(nur);
        if (u == 0) {
            ll += __logf(nur);
            float4* dp = (float4*)(dstBeta + ((size_t)g * 8192 + s) * 8);
            dp[0] = make_float4(pr[0] * rr, pr[1] * rr, pr[2] * rr, pr[3] * rr);
            dp[1] = make_float4(pr[4] * rr, pr[5] * rr, pr[6] * rr, pr[7] * rr);
        }
    }

    // per-wave ll partial: wave covers 8 subtrees -> llout[g][pg*4+wave]
    #pragma unroll
    for (int m = 1; m < 64; m <<= 1) ll += __shfl_xor(ll, m);
    if (lane == 0) llout[g * 1024 + pg * 4 + wave] = ll;
}

// ---------------- inner upsweep: two levels, scalar-M sweep (round-5) ----------------
template <int NSG, int SMID, int SROOT, int SRC_PT, int NSRC_TOT, int NDST_TOT>
__global__ __launch_bounds__(256) void up2(
    const float* __restrict__ MtN, const float* __restrict__ smBtN,
    const int* __restrict__ x,
    const float* __restrict__ srcBeta,   // [g][NSRC_TOT][8]
    float* __restrict__ dstBeta,         // [g][NDST_TOT][8]
    float* __restrict__ llout,           // [g][NSG]
    const float* __restrict__ llin, int llstride)
{
    constexpr int SPT = NSG * 4;
    int sg = blockIdx.x >> 2;
    int gq = blockIdx.x & 3;
    int wave = threadIdx.x >> 6;
    int lane = threadIdx.x & 63;
    int g = gq * 4 + wave;
    int gu = __builtin_amdgcn_readfirstlane(g);
    int u = lane & 7;
    int s = sg * 8 + (lane >> 3);
    int t = (s >= SPT) ? 1 : 0;
    int localS = s - t * SPT;
    int localP = localS * 8 + u;
    const int base = t * NT_NODES;

    float ll = 0.f;
    float bch[64];
    {
        const float4* sp = (const float4*)(srcBeta +
            ((size_t)g * NSRC_TOT + (size_t)t * SRC_PT + (size_t)localP * 8) * 8);
        #pragma unroll
        for (int v = 0; v < 16; ++v) {
            float4 f = sp[v];
            bch[4 * v + 0] = f.x; bch[4 * v + 1] = f.y;
            bch[4 * v + 2] = f.z; bch[4 * v + 3] = f.w;
        }
    }

    float pa[8] = {0.f, 0.f, 0.f, 0.f, 0.f, 0.f, 0.f, 0.f};
    const float* Mg = MtN + (gu << 9);
    #pragma unroll
    for (int k = 0; k < 64; ++k) {
        float b = bch[k];
        #pragma unroll
        for (int i = 0; i < 8; ++i) pa[i] = fmaf(b, Mg[k * 8 + i], pa[i]);
    }

    float bm[8];
    {
        int xm = x[base + SMID + localP];
        const float4* ep = (const float4*)(smBtN + ((gu << 5) + xm) * 8);
        float4 e0 = ep[0], e1 = ep[1];
        pa[0] *= e0.x; pa[1] *= e0.y; pa[2] *= e0.z; pa[3] *= e0.w;
        pa[4] *= e1.x; pa[5] *= e1.y; pa[6] *= e1.z; pa[7] *= e1.w;
        float nu = ((pa[0] + pa[1]) + (pa[2] + pa[3])) + ((pa[4] + pa[5]) + (pa[6] + pa[7]));
        ll += __logf(nu);
        float rn = __builtin_amdgcn_rcpf(nu);
        #pragma unroll
        for (int c = 0; c < 8; ++c) bm[c] = pa[c] * rn;
    }

    {
        float pr[8] = {0.f, 0.f, 0.f, 0.f, 0.f, 0.f, 0.f, 0.f};
        const float4* mr = (const float4*)(MtN + (gu << 9) + (u << 6));
        #pragma unroll
        for (int j = 0; j < 8; ++j) {
            float4 m0 = mr[j * 2], m1 = mr[j * 2 + 1];
            float b = bm[j];
            pr[0] = fmaf(b, m0.x, pr[0]); pr[1] = fmaf(b, m0.y, pr[1]);
            pr[2] = fmaf(b, m0.z, pr[2]); pr[3] = fmaf(b, m0.w, pr[3]);
            pr[4] = fmaf(b, m1.x, pr[4]); pr[5] = fmaf(b, m1.y, pr[5]);
            pr[6] = fmaf(b, m1.z, pr[6]); pr[7] = fmaf(b, m1.w, pr[7]);
        }
        #pragma unroll
        for (int m = 1; m <= 4; m <<= 1) {
            #pragma unroll
            for (int i = 0; i < 8; ++i) pr[i] += __shfl_xor(pr[i], m);
        }
        int xr = x[base + SROOT + localS];
        const float4* ep = (const float4*)(smBtN + ((gu << 5) + xr) * 8);
        float4 e0 = ep[0], e1 = ep[1];
        pr[0] *= e0.x; pr[1] *= e0.y; pr[2] *= e0.z; pr[3] *= e0.w;
        pr[4] *= e1.x; pr[5] *= e1.y; pr[6] *= e1.z; pr[7] *= e1.w;
        float nur = ((pr[0] + pr[1]) + (pr[2] + pr[3])) + ((pr[4] + pr[5]) + (pr[6] + pr[7]));
        float rr = __builtin_amdgcn_rcpf(nur);
        if (u == 0) {
            ll += __logf(nur);
            float4* dp = (float4*)(dstBeta + ((size_t)g * NDST_TOT + s) * 8);
            dp[0] = make_float4(pr[0] * rr, pr[1] * rr, pr[2] * rr, pr[3] * rr);
            dp[1] = make_float4(pr[4] * rr, pr[5] * rr, pr[6] * rr, pr[7] * rr);
        }
    }

    if (llin) ll += llin[g * llstride + sg * 64 + lane];
    #pragma unroll
    for (int m = 1; m < 64; m <<= 1) ll += __shfl_xor(ll, m);
    if (lane == 0) llout[g * NSG + sg] = ll;
}

// static 1-of-8 select by lane bits (7 cndmask)
__device__ __forceinline__ float sel8(const float v[8], bool c0, bool c1, bool c2) {
    float a0 = c0 ? v[1] : v[0];
    float a1 = c0 ? v[3] : v[2];
    float a2 = c0 ? v[5] : v[4];
    float a3 = c0 ? v[7] : v[6];
    float b0 = c1 ? a1 : a0;
    float b1 = c1 ? a3 : a2;
    return c2 ? b1 : b0;
}

// ---------------- tail: levels 2 -> 1 -> 0, one block per tree ----------------
__global__ __launch_bounds__(128) void tail(
    const float* __restrict__ Mt_old, const float* __restrict__ smBt_old,
    const int* __restrict__ x, const float* __restrict__ src /* [g][128][8] */,
    float* __restrict__ out, const float* __restrict__ ll2 /* [g][16] */)
{
    int b = blockIdx.x;
    int tid = threadIdx.x;
    int g = tid >> 3, j = tid & 7;
    bool c0 = (j & 1) != 0, c1 = (j & 2) != 0, c2 = (j & 4) != 0;
    const int nodebase = b * NT_NODES;

    float ll_priv = ll2[g * 16 + b * 8 + j];

    float M[64];
    {
        const float4* mp = (const float4*)(Mt_old + tid * 64);
        #pragma unroll
        for (int v = 0; v < 16; ++v) {
            float4 f = mp[v];
            M[4 * v + 0] = f.x; M[4 * v + 1] = f.y;
            M[4 * v + 2] = f.z; M[4 * v + 3] = f.w;
        }
    }

    int xm = x[nodebase + S1 + j];
    float ll = 0.f;
    float bmid[8];
    const float* sb = src + g * 1024 + b * 512 + j;

    #pragma unroll
    for (int u = 0; u < 8; ++u) {
        float bch[8];
        #pragma unroll
        for (int l = 0; l < 8; ++l) bch[l] = sb[(u * 8 + l) * 8];
        float pa[8];
        #pragma unroll
        for (int i = 0; i < 8; ++i) {
            float s = bch[0] * M[0 * 8 + i];
            #pragma unroll
            for (int l = 1; l < 8; ++l) s = fmaf(bch[l], M[l * 8 + i], s);
            pa[i] = s;
        }
        #pragma unroll
        for (int m = 1; m <= 4; m <<= 1) {
            #pragma unroll
            for (int i = 0; i < 8; ++i) pa[i] += __shfl_xor(pa[i], m);
        }
        int xv = __shfl(xm, u);
        const float4* bp = (const float4*)(smBt_old + xv * 128 + g * 8);
        float4 b0 = bp[0], b1 = bp[1];
        pa[0] *= b0.x; pa[1] *= b0.y; pa[2] *= b0.z; pa[3] *= b0.w;
        pa[4] *= b1.x; pa[5] *= b1.y; pa[6] *= b1.z; pa[7] *= b1.w;
        float nu = ((pa[0] + pa[1]) + (pa[2] + pa[3])) + ((pa[4] + pa[5]) + (pa[6] + pa[7]));
        ll += __logf(nu);
        bmid[u] = sel8(pa, c0, c1, c2) * __builtin_amdgcn_rcpf(nu);
    }

    {
        float pa[8];
        #pragma unroll
        for (int i = 0; i < 8; ++i) {
            float s = bmid[0] * M[0 * 8 + i];
            #pragma unroll
            for (int l = 1; l < 8; ++l) s = fmaf(bmid[l], M[l * 8 + i], s);
            pa[i] = s;
        }
        #pragma unroll
        for (int m = 1; m <= 4; m <<= 1) {
            #pragma unroll
            for (int i = 0; i < 8; ++i) pa[i] += __shfl_xor(pa[i], m);
        }
        int xv = x[nodebase + S0];
        const float4* bp = (const float4*)(smBt_old + xv * 128 + g * 8);
        float4 b0 = bp[0], b1 = bp[1];
        pa[0] *= b0.x; pa[1] *= b0.y; pa[2] *= b0.z; pa[3] *= b0.w;
        pa[4] *= b1.x; pa[5] *= b1.y; pa[6] *= b1.z; pa[7] *= b1.w;
        float nu = ((pa[0] + pa[1]) + (pa[2] + pa[3])) + ((pa[4] + pa[5]) + (pa[6] + pa[7]));
        ll += __logf(nu);
    }

    float s = ll_priv;
    s += __shfl_xor(s, 1); s += __shfl_xor(s, 2); s += __shfl_xor(s, 4);
    if (j == 0) out[b * 16 + g] = s + ll;
}

extern "C" void kernel_launch(void* const* d_in, const int* in_sizes, int n_in,
                              void* d_out, int out_size, void* d_ws, size_t ws_size,
                              hipStream_t stream)
{
    const float* A  = (const float*)d_in[0];
    const float* B  = (const float*)d_in[1];
    const float* Pi = (const float*)d_in[2];
    const float* SP = (const float*)d_in[3];
    const int*   x  = (const int*)d_in[4];

    float* ws      = (float*)d_ws;
    float* Mt_old  = ws;                      // 8192
    float* MtN     = Mt_old + 8192;           // 8192
    float* smBt_o  = MtN + 8192;              // 4096
    float* smBtN   = smBt_o + 4096;           // 4096
    float* Tt      = smBtN + 4096;            // 32768
    float* ltab    = Tt + 32768;              // 4096
    float* lv4     = ltab + 4096;             // 16*8192*8 = 1048576
    float* lv2     = lv4 + 1048576;           // 16*128*8  = 16384
    float* ll1     = lv2 + 16384;             // 16*1024   = 16384
    float* ll2     = ll1 + 16384;             // 16*16     = 256
    float* out     = (float*)d_out;

    stage0T<<<16, 256, 0, stream>>>(A, B, Pi, SP, Mt_old, MtN, smBt_o, smBtN, Tt, ltab);
    // levels 6 -> 5 -> 4 via LDS-staged T table
    upleaf<<<4096, 256, 0, stream>>>(MtN, smBtN, Tt, ltab, x, lv4, ll1);
    // levels 4 -> 3 -> 2 (+ fold ll1)
    up2<16, S3, S2, 4096, 8192, 128><<<64, 256, 0, stream>>>(
        MtN, smBtN, x, lv4, lv2, ll2, ll1, 1024);
    // levels 2 -> 1 -> 0 (+ fold ll2), writes out[2][16]
    tail<<<2, 128, 0, stream>>>(Mt_old, smBt_o, x, lv2, out, ll2);
}

// Round 8
// 59.034 us; speedup vs baseline: 1.5857x; 1.0963x over previous
//
#include <hip/hip_runtime.h>

// Bottom-up HTMM upward pass.
// Round-8: leaf kernel's LDS tables are bf16-packed (T row = 4 dwords bf16 +
// 1 dword f32 ltab, stride 5; gcd(5,32)=1 keeps the symbol->bank map
// bijective => divergent reads stay conflict-free), and each thread handles
// TWO mid-parents (half the waves, fills amortized).
// Tree structure implicit: starts[d]=(8^d-1)/7, child position == local%8.

constexpr int NT_NODES = 299593;
constexpr int S0 = 0, S1 = 1, S2 = 9, S3 = 73, S4 = 585, S5 = 4681, S6 = 37449;

__device__ __forceinline__ unsigned bfbits(float x) {   // f32 -> bf16 bits, RNE
    unsigned v = __float_as_uint(x);
    return (v + 0x7fffu + ((v >> 16) & 1u)) >> 16;
}

// ---------------- stage0T: one block per g — softmaxes + packed tables ----------------
//   MtN   [g][l][j][i] : 8192 f32  (= smSP[l,g]*smA[i,j,l,g])
//   Mt_old[g][j][l][i] : 8192 f32  (tail layout)
//   smBtN [g][m][c]    : 4096 f32
//   smBt_old[m][g][c]  : 4096 f32  (tail layout)
//   Tp    [g][k][256]  : 16*5*256 uint (k=0..3 bf16 pairs of T, k=4 f32 ltab)
//   EMp   [g][k][32]   : 16*4*32 uint  (bf16 pairs of emission rows)
__global__ __launch_bounds__(256) void stage0T(
    const float* __restrict__ A, const float* __restrict__ B,
    const float* __restrict__ Pi, const float* __restrict__ SP,
    float* __restrict__ Mt_old, float* __restrict__ MtN,
    float* __restrict__ smBt_old, float* __restrict__ smBtN,
    unsigned* __restrict__ Tp, unsigned* __restrict__ EMp)
{
    int g = blockIdx.x;
    int tid = threadIdx.x;
    __shared__ __align__(16) float mL[512];   // [l][j][i]
    __shared__ __align__(16) float bLs[256];  // [m][c]
    __shared__ __align__(16) float piLs[64];  // [l][c]

    float sp[8];
    {
        float mx = -1e30f;
        #pragma unroll
        for (int l = 0; l < 8; ++l) { sp[l] = SP[l * 16 + g]; mx = fmaxf(mx, sp[l]); }
        float s = 0.f;
        #pragma unroll
        for (int l = 0; l < 8; ++l) { sp[l] = __expf(sp[l] - mx); s += sp[l]; }
        float r = 1.f / s;
        #pragma unroll
        for (int l = 0; l < 8; ++l) sp[l] *= r;
    }

    if (tid < 64) {
        int j = tid & 7, l = tid >> 3;
        float a[8]; float mx = -1e30f;
        #pragma unroll
        for (int i = 0; i < 8; ++i) { a[i] = A[((i * 8 + j) * 8 + l) * 16 + g]; mx = fmaxf(mx, a[i]); }
        float s = 0.f;
        #pragma unroll
        for (int i = 0; i < 8; ++i) { a[i] = __expf(a[i] - mx); s += a[i]; }
        float scale = sp[l] / s;
        #pragma unroll
        for (int i = 0; i < 8; ++i) {
            float m = a[i] * scale;
            mL[(l * 8 + j) * 8 + i] = m;
            MtN[((g * 8 + l) * 8 + j) * 8 + i] = m;
            Mt_old[((g * 8 + j) * 8 + l) * 8 + i] = m;
        }
    } else if (tid < 72) {
        int c = tid - 64;
        float vv[32]; float mx = -1e30f;
        #pragma unroll
        for (int m = 0; m < 32; ++m) { vv[m] = B[(c * 32 + m) * 16 + g]; mx = fmaxf(mx, vv[m]); }
        float s = 0.f;
        #pragma unroll
        for (int m = 0; m < 32; ++m) { vv[m] = __expf(vv[m] - mx); s += vv[m]; }
        float r = 1.f / s;
        #pragma unroll
        for (int m = 0; m < 32; ++m) {
            float p = vv[m] * r;
            bLs[m * 8 + c] = p;
            smBt_old[(m * 16 + g) * 8 + c] = p;
            smBtN[(g * 32 + m) * 8 + c] = p;
        }
    } else if (tid < 80) {
        int l = tid - 72;
        float a[8]; float mx = -1e30f;
        #pragma unroll
        for (int c = 0; c < 8; ++c) { a[c] = Pi[(c * 8 + l) * 16 + g]; mx = fmaxf(mx, a[c]); }
        float s = 0.f;
        #pragma unroll
        for (int c = 0; c < 8; ++c) { a[c] = __expf(a[c] - mx); s += a[c]; }
        float r = 1.f / s;
        #pragma unroll
        for (int c = 0; c < 8; ++c) piLs[l * 8 + c] = a[c] * r;
    }
    __syncthreads();

    // per (l,m): nu, ltab, packed T row
    {
        int m = tid & 31, l = tid >> 5;
        float pb[8]; float w = 0.f;
        #pragma unroll
        for (int c = 0; c < 8; ++c) { pb[c] = piLs[l * 8 + c] * bLs[m * 8 + c]; w += pb[c]; }
        float rw = 1.f / w;
        float t[8];
        #pragma unroll
        for (int i = 0; i < 8; ++i) t[i] = 0.f;
        #pragma unroll
        for (int c = 0; c < 8; ++c) {
            float p = pb[c];
            #pragma unroll
            for (int i = 0; i < 8; ++i) t[i] = fmaf(p, mL[(l * 8 + c) * 8 + i], t[i]);
        }
        #pragma unroll
        for (int k = 0; k < 4; ++k) {
            unsigned lo = bfbits(t[2 * k] * rw), hi = bfbits(t[2 * k + 1] * rw);
            Tp[(g * 5 + k) * 256 + tid] = lo | (hi << 16);
        }
        Tp[(g * 5 + 4) * 256 + tid] = __float_as_uint(__logf(w));
    }
    // packed emission rows
    if (tid < 32) {
        #pragma unroll
        for (int k = 0; k < 4; ++k) {
            unsigned lo = bfbits(bLs[tid * 8 + 2 * k]), hi = bfbits(bLs[tid * 8 + 2 * k + 1]);
            EMp[(g * 4 + k) * 32 + tid] = lo | (hi << 16);
        }
    }
}

// ---------------- leaf upsweep: levels 6 -> 5 -> 4, packed LDS tables ----------------
// Block = 256 thr = 4 waves, ONE g per block, 2 mid-parents per thread.
// grid.x = 128 parent-groups * 16 g = 2048.
__global__ __launch_bounds__(256) void upleaf(
    const float* __restrict__ MtN, const unsigned* __restrict__ Tp,
    const unsigned* __restrict__ EMp, const int* __restrict__ x,
    float* __restrict__ dstBeta,   // [g][8192][8]
    float* __restrict__ llout)     // [g][512]
{
    __shared__ unsigned TL[256 * 5 + 32 * 5];   // T rows, then emission rows

    int bid = blockIdx.x;
    int g = bid & 15;
    int pg = bid >> 4;                 // 0..127
    int tid = threadIdx.x;
    int wave = tid >> 6;
    int lane = tid & 63;
    int gu = __builtin_amdgcn_readfirstlane(g);
    int u = tid & 7;

    // fill LDS (coalesced global, stride-5 LDS writes: 2-way aliasing = free)
    #pragma unroll
    for (int k = 0; k < 5; ++k)
        TL[tid * 5 + k] = Tp[(gu * 5 + k) * 256 + tid];
    if (tid < 32) {
        #pragma unroll
        for (int k = 0; k < 4; ++k)
            TL[1280 + tid * 5 + k] = EMp[(gu * 4 + k) * 32 + tid];
    }
    __syncthreads();

    float ll = 0.f;
    #pragma unroll
    for (int rep = 0; rep < 2; ++rep) {
        int s = pg * 64 + rep * 32 + (tid >> 3);   // global level-4 subtree
        int t = (s >= 4096) ? 1 : 0;
        int localS = s - t * 4096;
        int localP = localS * 8 + u;
        const int base = t * NT_NODES;

        int xl[8];
        {
            const int xb = base + S6 + localP * 8;
            #pragma unroll
            for (int l = 0; l < 8; ++l) xl[l] = x[xb + l];
        }

        float pa[8] = {0.f, 0.f, 0.f, 0.f, 0.f, 0.f, 0.f, 0.f};
        #pragma unroll
        for (int l = 0; l < 8; ++l) {
            int r5 = (l * 32 + xl[l]) * 5;
            unsigned u0 = TL[r5], u1 = TL[r5 + 1], u2 = TL[r5 + 2], u3 = TL[r5 + 3];
            ll += __uint_as_float(TL[r5 + 4]);
            pa[0] += __uint_as_float(u0 << 16); pa[1] += __uint_as_float(u0 & 0xffff0000u);
            pa[2] += __uint_as_float(u1 << 16); pa[3] += __uint_as_float(u1 & 0xffff0000u);
            pa[4] += __uint_as_float(u2 << 16); pa[5] += __uint_as_float(u2 & 0xffff0000u);
            pa[6] += __uint_as_float(u3 << 16); pa[7] += __uint_as_float(u3 & 0xffff0000u);
        }

        // mid emission + normalize
        float bm[8];
        {
            int xm = x[base + S5 + localP];
            int e5 = 1280 + xm * 5;
            unsigned e0 = TL[e5], e1 = TL[e5 + 1], e2 = TL[e5 + 2], e3 = TL[e5 + 3];
            pa[0] *= __uint_as_float(e0 << 16); pa[1] *= __uint_as_float(e0 & 0xffff0000u);
            pa[2] *= __uint_as_float(e1 << 16); pa[3] *= __uint_as_float(e1 & 0xffff0000u);
            pa[4] *= __uint_as_float(e2 << 16); pa[5] *= __uint_as_float(e2 & 0xffff0000u);
            pa[6] *= __uint_as_float(e3 << 16); pa[7] *= __uint_as_float(e3 & 0xffff0000u);
            float nu = ((pa[0] + pa[1]) + (pa[2] + pa[3])) + ((pa[4] + pa[5]) + (pa[6] + pa[7]));
            ll += __logf(nu);
            float rn = __builtin_amdgcn_rcpf(nu);
            #pragma unroll
            for (int c = 0; c < 8; ++c) bm[c] = pa[c] * rn;
        }

        // root: partial over own child-position u, butterfly over octet
        {
            float pr[8] = {0.f, 0.f, 0.f, 0.f, 0.f, 0.f, 0.f, 0.f};
            const float4* mr = (const float4*)(MtN + (gu << 9) + (u << 6));
            #pragma unroll
            for (int j = 0; j < 8; ++j) {
                float4 m0 = mr[j * 2], m1 = mr[j * 2 + 1];
                float b = bm[j];
                pr[0] = fmaf(b, m0.x, pr[0]); pr[1] = fmaf(b, m0.y, pr[1]);
                pr[2] = fmaf(b, m0.z, pr[2]); pr[3] = fmaf(b, m0.w, pr[3]);
                pr[4] = fmaf(b, m1.x, pr[4]); pr[5] = fmaf(b, m1.y, pr[5]);
                pr[6] = fmaf(b, m1.z, pr[6]); pr[7] = fmaf(b, m1.w, pr[7]);
            }
            #pragma unroll
            for (int m = 1; m <= 4; m <<= 1) {
                #pragma unroll
                for (int i = 0; i < 8; ++i) pr[i] += __shfl_xor(pr[i], m);
            }
            int xr = x[base + S4 + localS];
            int e5 = 1280 + xr * 5;
            unsigned e0 = TL[e5], e1 = TL[e5 + 1], e2 = TL[e5 + 2], e3 = TL[e5 + 3];
            pr[0] *= __uint_as_float(e0 << 16); pr[1] *= __uint_as_float(e0 & 0xffff0000u);
            pr[2] *= __uint_as_float(e1 << 16); pr[3] *= __uint_as_float(e1 & 0xffff0000u);
            pr[4] *= __uint_as_float(e2 << 16); pr[5] *= __uint_as_float(e2 & 0xffff0000u);
            pr[6] *= __uint_as_float(e3 << 16); pr[7] *= __uint_as_float(e3 & 0xffff0000u);
            float nur = ((pr[0] + pr[1]) + (pr[2] + pr[3])) + ((pr[4] + pr[5]) + (pr[6] + pr[7]));
            float rr = __builtin_amdgcn_rcpf(nur);
            if (u == 0) {
                ll += __logf(nur);
                float4* dp = (float4*)(dstBeta + ((size_t)g * 8192 + s) * 8);
                dp[0] = make_float4(pr[0] * rr, pr[1] * rr, pr[2] * rr, pr[3] * rr);
                dp[1] = make_float4(pr[4] * rr, pr[5] * rr, pr[6] * rr, pr[7] * rr);
            }
        }
    }

    #pragma unroll
    for (int m = 1; m < 64; m <<= 1) ll += __shfl_xor(ll, m);
    if (lane == 0) llout[g * 512 + pg * 4 + wave] = ll;
}

// ---------------- inner upsweep: two levels, scalar-M sweep ----------------
template <int NSG, int SMID, int SROOT, int SRC_PT, int NSRC_TOT, int NDST_TOT>
__global__ __launch_bounds__(256) void up2(
    const float* __restrict__ MtN, const float* __restrict__ smBtN,
    const int* __restrict__ x,
    const float* __restrict__ srcBeta,   // [g][NSRC_TOT][8]
    float* __restrict__ dstBeta,         // [g][NDST_TOT][8]
    float* __restrict__ llout,           // [g][NSG]
    const float* __restrict__ llin)      // [g][512] wave partials (or null)
{
    constexpr int SPT = NSG * 4;
    int sg = blockIdx.x >> 2;
    int gq = blockIdx.x & 3;
    int wave = threadIdx.x >> 6;
    int lane = threadIdx.x & 63;
    int g = gq * 4 + wave;
    int gu = __builtin_amdgcn_readfirstlane(g);
    int u = lane & 7;
    int s = sg * 8 + (lane >> 3);
    int t = (s >= SPT) ? 1 : 0;
    int localS = s - t * SPT;
    int localP = localS * 8 + u;
    const int base = t * NT_NODES;

    float ll = 0.f;
    if (llin && lane < 32) ll = llin[g * 512 + sg * 32 + lane];

    float bch[64];
    {
        const float4* sp = (const float4*)(srcBeta +
            ((size_t)g * NSRC_TOT + (size_t)t * SRC_PT + (size_t)localP * 8) * 8);
        #pragma unroll
        for (int v = 0; v < 16; ++v) {
            float4 f = sp[v];
            bch[4 * v + 0] = f.x; bch[4 * v + 1] = f.y;
            bch[4 * v + 2] = f.z; bch[4 * v + 3] = f.w;
        }
    }

    float pa[8] = {0.f, 0.f, 0.f, 0.f, 0.f, 0.f, 0.f, 0.f};
    const float* Mg = MtN + (gu << 9);
    #pragma unroll
    for (int k = 0; k < 64; ++k) {
        float b = bch[k];
        #pragma unroll
        for (int i = 0; i < 8; ++i) pa[i] = fmaf(b, Mg[k * 8 + i], pa[i]);
    }

    float bm[8];
    {
        int xm = x[base + SMID + localP];
        const float4* ep = (const float4*)(smBtN + ((gu << 5) + xm) * 8);
        float4 e0 = ep[0], e1 = ep[1];
        pa[0] *= e0.x; pa[1] *= e0.y; pa[2] *= e0.z; pa[3] *= e0.w;
        pa[4] *= e1.x; pa[5] *= e1.y; pa[6] *= e1.z; pa[7] *= e1.w;
        float nu = ((pa[0] + pa[1]) + (pa[2] + pa[3])) + ((pa[4] + pa[5]) + (pa[6] + pa[7]));
        ll += __logf(nu);
        float rn = __builtin_amdgcn_rcpf(nu);
        #pragma unroll
        for (int c = 0; c < 8; ++c) bm[c] = pa[c] * rn;
    }

    {
        float pr[8] = {0.f, 0.f, 0.f, 0.f, 0.f, 0.f, 0.f, 0.f};
        const float4* mr = (const float4*)(MtN + (gu << 9) + (u << 6));
        #pragma unroll
        for (int j = 0; j < 8; ++j) {
            float4 m0 = mr[j * 2], m1 = mr[j * 2 + 1];
            float b = bm[j];
            pr[0] = fmaf(b, m0.x, pr[0]); pr[1] = fmaf(b, m0.y, pr[1]);
            pr[2] = fmaf(b, m0.z, pr[2]); pr[3] = fmaf(b, m0.w, pr[3]);
            pr[4] = fmaf(b, m1.x, pr[4]); pr[5] = fmaf(b, m1.y, pr[5]);
            pr[6] = fmaf(b, m1.z, pr[6]); pr[7] = fmaf(b, m1.w, pr[7]);
        }
        #pragma unroll
        for (int m = 1; m <= 4; m <<= 1) {
            #pragma unroll
            for (int i = 0; i < 8; ++i) pr[i] += __shfl_xor(pr[i], m);
        }
        int xr = x[base + SROOT + localS];
        const float4* ep = (const float4*)(smBtN + ((gu << 5) + xr) * 8);
        float4 e0 = ep[0], e1 = ep[1];
        pr[0] *= e0.x; pr[1] *= e0.y; pr[2] *= e0.z; pr[3] *= e0.w;
        pr[4] *= e1.x; pr[5] *= e1.y; pr[6] *= e1.z; pr[7] *= e1.w;
        float nur = ((pr[0] + pr[1]) + (pr[2] + pr[3])) + ((pr[4] + pr[5]) + (pr[6] + pr[7]));
        float rr = __builtin_amdgcn_rcpf(nur);
        if (u == 0) {
            ll += __logf(nur);
            float4* dp = (float4*)(dstBeta + ((size_t)g * NDST_TOT + s) * 8);
            dp[0] = make_float4(pr[0] * rr, pr[1] * rr, pr[2] * rr, pr[3] * rr);
            dp[1] = make_float4(pr[4] * rr, pr[5] * rr, pr[6] * rr, pr[7] * rr);
        }
    }

    #pragma unroll
    for (int m = 1; m < 64; m <<= 1) ll += __shfl_xor(ll, m);
    if (lane == 0) llout[g * NSG + sg] = ll;
}

// static 1-of-8 select by lane bits (7 cndmask)
__device__ __forceinline__ float sel8(const float v[8], bool c0, bool c1, bool c2) {
    float a0 = c0 ? v[1] : v[0];
    float a1 = c0 ? v[3] : v[2];
    float a2 = c0 ? v[5] : v[4];
    float a3 = c0 ? v[7] : v[6];
    float b0 = c1 ? a1 : a0;
    float b1 = c1 ? a3 : a2;
    return c2 ? b1 : b0;
}

// ---------------- tail: levels 2 -> 1 -> 0, one block per tree ----------------
__global__ __launch_bounds__(128) void tail(
    const float* __restrict__ Mt_old, const float* __restrict__ smBt_old,
    const int* __restrict__ x, const float* __restrict__ src /* [g][128][8] */,
    float* __restrict__ out, const float* __restrict__ ll2 /* [g][16] */)
{
    int b = blockIdx.x;
    int tid = threadIdx.x;
    int g = tid >> 3, j = tid & 7;
    bool c0 = (j & 1) != 0, c1 = (j & 2) != 0, c2 = (j & 4) != 0;
    const int nodebase = b * NT_NODES;

    float ll_priv = ll2[g * 16 + b * 8 + j];

    float M[64];
    {
        const float4* mp = (const float4*)(Mt_old + tid * 64);
        #pragma unroll
        for (int v = 0; v < 16; ++v) {
            float4 f = mp[v];
            M[4 * v + 0] = f.x; M[4 * v + 1] = f.y;
            M[4 * v + 2] = f.z; M[4 * v + 3] = f.w;
        }
    }

    int xm = x[nodebase + S1 + j];
    float ll = 0.f;
    float bmid[8];
    const float* sb = src + g * 1024 + b * 512 + j;

    #pragma unroll
    for (int u = 0; u < 8; ++u) {
        float bch[8];
        #pragma unroll
        for (int l = 0; l < 8; ++l) bch[l] = sb[(u * 8 + l) * 8];
        float pa[8];
        #pragma unroll
        for (int i = 0; i < 8; ++i) {
            float s = bch[0] * M[0 * 8 + i];
            #pragma unroll
            for (int l = 1; l < 8; ++l) s = fmaf(bch[l], M[l * 8 + i], s);
            pa[i] = s;
        }
        #pragma unroll
        for (int m = 1; m <= 4; m <<= 1) {
            #pragma unroll
            for (int i = 0; i < 8; ++i) pa[i] += __shfl_xor(pa[i], m);
        }
        int xv = __shfl(xm, u);
        const float4* bp = (const float4*)(smBt_old + xv * 128 + g * 8);
        float4 b0 = bp[0], b1 = bp[1];
        pa[0] *= b0.x; pa[1] *= b0.y; pa[2] *= b0.z; pa[3] *= b0.w;
        pa[4] *= b1.x; pa[5] *= b1.y; pa[6] *= b1.z; pa[7] *= b1.w;
        float nu = ((pa[0] + pa[1]) + (pa[2] + pa[3])) + ((pa[4] + pa[5]) + (pa[6] + pa[7]));
        ll += __logf(nu);
        bmid[u] = sel8(pa, c0, c1, c2) * __builtin_amdgcn_rcpf(nu);
    }

    {
        float pa[8];
        #pragma unroll
        for (int i = 0; i < 8; ++i) {
            float s = bmid[0] * M[0 * 8 + i];
            #pragma unroll
            for (int l = 1; l < 8; ++l) s = fmaf(bmid[l], M[l * 8 + i], s);
            pa[i] = s;
        }
        #pragma unroll
        for (int m = 1; m <= 4; m <<= 1) {
            #pragma unroll
            for (int i = 0; i < 8; ++i) pa[i] += __shfl_xor(pa[i], m);
        }
        int xv = x[nodebase + S0];
        const float4* bp = (const float4*)(smBt_old + xv * 128 + g * 8);
        float4 b0 = bp[0], b1 = bp[1];
        pa[0] *= b0.x; pa[1] *= b0.y; pa[2] *= b0.z; pa[3] *= b0.w;
        pa[4] *= b1.x; pa[5] *= b1.y; pa[6] *= b1.z; pa[7] *= b1.w;
        float nu = ((pa[0] + pa[1]) + (pa[2] + pa[3])) + ((pa[4] + pa[5]) + (pa[6] + pa[7]));
        ll += __logf(nu);
    }

    float s = ll_priv;
    s += __shfl_xor(s, 1); s += __shfl_xor(s, 2); s += __shfl_xor(s, 4);
    if (j == 0) out[b * 16 + g] = s + ll;
}

extern "C" void kernel_launch(void* const* d_in, const int* in_sizes, int n_in,
                              void* d_out, int out_size, void* d_ws, size_t ws_size,
                              hipStream_t stream)
{
    const float* A  = (const float*)d_in[0];
    const float* B  = (const float*)d_in[1];
    const float* Pi = (const float*)d_in[2];
    const float* SP = (const float*)d_in[3];
    const int*   x  = (const int*)d_in[4];

    float* ws      = (float*)d_ws;
    float* Mt_old  = ws;                      // 8192
    float* MtN     = Mt_old + 8192;           // 8192
    float* smBt_o  = MtN + 8192;              // 4096
    float* smBtN   = smBt_o + 4096;           // 4096
    unsigned* Tp   = (unsigned*)(smBtN + 4096);   // 16*5*256 = 20480
    unsigned* EMp  = Tp + 20480;              // 16*4*32 = 2048
    float* lv4     = (float*)(EMp + 2048);    // 16*8192*8 = 1048576
    float* lv2     = lv4 + 1048576;           // 16*128*8  = 16384
    float* ll1     = lv2 + 16384;             // 16*512    = 8192
    float* ll2     = ll1 + 8192;              // 16*16     = 256
    float* out     = (float*)d_out;

    stage0T<<<16, 256, 0, stream>>>(A, B, Pi, SP, Mt_old, MtN, smBt_o, smBtN, Tp, EMp);
    // levels 6 -> 5 -> 4 via packed LDS tables, 2 parents/thread
    upleaf<<<2048, 256, 0, stream>>>(MtN, Tp, EMp, x, lv4, ll1);
    // levels 4 -> 3 -> 2 (+ fold ll1 wave partials)
    up2<16, S3, S2, 4096, 8192, 128><<<64, 256, 0, stream>>>(
        MtN, smBtN, x, lv4, lv2, ll2, ll1);
    // levels 2 -> 1 -> 0 (+ fold ll2), writes out[2][16]
    tail<<<2, 128, 0, stream>>>(Mt_old, smBt_o, x, lv2, out, ll2);
}

// Round 9
// 52.688 us; speedup vs baseline: 1.7766x; 1.1204x over previous
//
#include <hip/hip_runtime.h>

// Bottom-up HTMM upward pass — 3 launches.
// upleaf: levels 6->5->4->3 (block = 32 level-4 subtrees = 4 level-3 nodes,
//         packed bf16 LDS tables, level-4 betas stashed in LDS, only level-3
//         betas hit global memory).
// uptop : one block per g, levels 3->2->1->0 + all ll folding -> out[2][16].
// Tree structure implicit: starts[d]=(8^d-1)/7, child position == local%8.

constexpr int NT_NODES = 299593;
constexpr int S0 = 0, S1 = 1, S2 = 9, S3 = 73, S4 = 585, S5 = 4681, S6 = 37449;

__device__ __forceinline__ unsigned bfbits(float x) {   // f32 -> bf16 bits, RNE
    unsigned v = __float_as_uint(x);
    return (v + 0x7fffu + ((v >> 16) & 1u)) >> 16;
}

// static 1-of-8 select by lane bits (7 cndmask)
__device__ __forceinline__ float sel8(const float v[8], bool c0, bool c1, bool c2) {
    float a0 = c0 ? v[1] : v[0];
    float a1 = c0 ? v[3] : v[2];
    float a2 = c0 ? v[5] : v[4];
    float a3 = c0 ? v[7] : v[6];
    float b0 = c1 ? a1 : a0;
    float b1 = c1 ? a3 : a2;
    return c2 ? b1 : b0;
}

// ---------------- stage0T: one block per g — softmaxes + packed tables ----------------
//   MtN   [g][l][j][i] : 8192 f32  (= smSP[l,g]*smA[i,j,l,g])
//   smBtN [g][m][c]    : 4096 f32
//   Tp    [g][k][256]  : k=0..3 bf16 pairs of T row, k=4 f32 ltab
//   EMp   [g][k][32]   : bf16 pairs of emission rows
__global__ __launch_bounds__(256) void stage0T(
    const float* __restrict__ A, const float* __restrict__ B,
    const float* __restrict__ Pi, const float* __restrict__ SP,
    float* __restrict__ MtN, float* __restrict__ smBtN,
    unsigned* __restrict__ Tp, unsigned* __restrict__ EMp)
{
    int g = blockIdx.x;
    int tid = threadIdx.x;
    __shared__ __align__(16) float mL[512];   // [l][j][i]
    __shared__ __align__(16) float bLs[256];  // [m][c]
    __shared__ __align__(16) float piLs[64];  // [l][c]

    float sp[8];
    {
        float mx = -1e30f;
        #pragma unroll
        for (int l = 0; l < 8; ++l) { sp[l] = SP[l * 16 + g]; mx = fmaxf(mx, sp[l]); }
        float s = 0.f;
        #pragma unroll
        for (int l = 0; l < 8; ++l) { sp[l] = __expf(sp[l] - mx); s += sp[l]; }
        float r = 1.f / s;
        #pragma unroll
        for (int l = 0; l < 8; ++l) sp[l] *= r;
    }

    if (tid < 64) {
        int j = tid & 7, l = tid >> 3;
        float a[8]; float mx = -1e30f;
        #pragma unroll
        for (int i = 0; i < 8; ++i) { a[i] = A[((i * 8 + j) * 8 + l) * 16 + g]; mx = fmaxf(mx, a[i]); }
        float s = 0.f;
        #pragma unroll
        for (int i = 0; i < 8; ++i) { a[i] = __expf(a[i] - mx); s += a[i]; }
        float scale = sp[l] / s;
        #pragma unroll
        for (int i = 0; i < 8; ++i) {
            float m = a[i] * scale;
            mL[(l * 8 + j) * 8 + i] = m;
            MtN[((g * 8 + l) * 8 + j) * 8 + i] = m;
        }
    } else if (tid < 72) {
        int c = tid - 64;
        float vv[32]; float mx = -1e30f;
        #pragma unroll
        for (int m = 0; m < 32; ++m) { vv[m] = B[(c * 32 + m) * 16 + g]; mx = fmaxf(mx, vv[m]); }
        float s = 0.f;
        #pragma unroll
        for (int m = 0; m < 32; ++m) { vv[m] = __expf(vv[m] - mx); s += vv[m]; }
        float r = 1.f / s;
        #pragma unroll
        for (int m = 0; m < 32; ++m) {
            float p = vv[m] * r;
            bLs[m * 8 + c] = p;
            smBtN[(g * 32 + m) * 8 + c] = p;
        }
    } else if (tid < 80) {
        int l = tid - 72;
        float a[8]; float mx = -1e30f;
        #pragma unroll
        for (int c = 0; c < 8; ++c) { a[c] = Pi[(c * 8 + l) * 16 + g]; mx = fmaxf(mx, a[c]); }
        float s = 0.f;
        #pragma unroll
        for (int c = 0; c < 8; ++c) { a[c] = __expf(a[c] - mx); s += a[c]; }
        float r = 1.f / s;
        #pragma unroll
        for (int c = 0; c < 8; ++c) piLs[l * 8 + c] = a[c] * r;
    }
    __syncthreads();

    // per (l,m): nu, ltab, packed T row
    {
        int m = tid & 31, l = tid >> 5;
        float pb[8]; float w = 0.f;
        #pragma unroll
        for (int c = 0; c < 8; ++c) { pb[c] = piLs[l * 8 + c] * bLs[m * 8 + c]; w += pb[c]; }
        float rw = 1.f / w;
        float t[8];
        #pragma unroll
        for (int i = 0; i < 8; ++i) t[i] = 0.f;
        #pragma unroll
        for (int c = 0; c < 8; ++c) {
            float p = pb[c];
            #pragma unroll
            for (int i = 0; i < 8; ++i) t[i] = fmaf(p, mL[(l * 8 + c) * 8 + i], t[i]);
        }
        #pragma unroll
        for (int k = 0; k < 4; ++k) {
            unsigned lo = bfbits(t[2 * k] * rw), hi = bfbits(t[2 * k + 1] * rw);
            Tp[(g * 5 + k) * 256 + tid] = lo | (hi << 16);
        }
        Tp[(g * 5 + 4) * 256 + tid] = __float_as_uint(__logf(w));
    }
    if (tid < 32) {
        #pragma unroll
        for (int k = 0; k < 4; ++k) {
            unsigned lo = bfbits(bLs[tid * 8 + 2 * k]), hi = bfbits(bLs[tid * 8 + 2 * k + 1]);
            EMp[(g * 4 + k) * 32 + tid] = lo | (hi << 16);
        }
    }
}

// ---------------- upleaf: levels 6 -> 5 -> 4 -> 3 ----------------
// grid = 256 pg-groups * 16 g = 4096 blocks, 256 thr, 1 mid-parent/thread.
// Block covers 32 level-4 subtrees (one tree only: 32-aligned) = 4 level-3
// nodes. Level-4 betas stay in LDS; only level-3 betas go to global.
__global__ __launch_bounds__(256) void upleaf(
    const float* __restrict__ MtN, const unsigned* __restrict__ Tp,
    const unsigned* __restrict__ EMp, const int* __restrict__ x,
    float* __restrict__ lv3,     // [g][1024][8]
    float* __restrict__ llout)   // [g][256]
{
    __shared__ unsigned TL[256 * 5 + 32 * 5];
    __shared__ __align__(16) float b4[32 * 8];
    __shared__ float llp[4];

    int bid = blockIdx.x;
    int g = bid & 15;
    int pg = bid >> 4;                 // 0..255
    int tid = threadIdx.x;
    int wave = tid >> 6;
    int lane = tid & 63;
    int gu = __builtin_amdgcn_readfirstlane(g);
    int u = tid & 7;
    int s = pg * 32 + (tid >> 3);      // global level-4 subtree 0..8191
    int t = (s >= 4096) ? 1 : 0;
    int localS = s - t * 4096;
    int localP = localS * 8 + u;
    const int base = t * NT_NODES;

    // fill LDS tables (stride 5: gcd(5,32)=1 -> divergent reads conflict-free)
    #pragma unroll
    for (int k = 0; k < 5; ++k)
        TL[tid * 5 + k] = Tp[(gu * 5 + k) * 256 + tid];
    if (tid < 32) {
        #pragma unroll
        for (int k = 0; k < 4; ++k)
            TL[1280 + tid * 5 + k] = EMp[(gu * 4 + k) * 32 + tid];
    }

    // hoist all x loads
    int xl[8];
    {
        const int xb = base + S6 + localP * 8;
        #pragma unroll
        for (int l = 0; l < 8; ++l) xl[l] = x[xb + l];
    }
    int xm = x[base + S5 + localP];
    int xr = x[base + S4 + localS];
    __syncthreads();

    float ll = 0.f;

    // ---- leaves ----
    float pa[8] = {0.f, 0.f, 0.f, 0.f, 0.f, 0.f, 0.f, 0.f};
    #pragma unroll
    for (int l = 0; l < 8; ++l) {
        int r5 = (l * 32 + xl[l]) * 5;
        unsigned u0 = TL[r5], u1 = TL[r5 + 1], u2 = TL[r5 + 2], u3 = TL[r5 + 3];
        ll += __uint_as_float(TL[r5 + 4]);
        pa[0] += __uint_as_float(u0 << 16); pa[1] += __uint_as_float(u0 & 0xffff0000u);
        pa[2] += __uint_as_float(u1 << 16); pa[3] += __uint_as_float(u1 & 0xffff0000u);
        pa[4] += __uint_as_float(u2 << 16); pa[5] += __uint_as_float(u2 & 0xffff0000u);
        pa[6] += __uint_as_float(u3 << 16); pa[7] += __uint_as_float(u3 & 0xffff0000u);
    }

    // ---- mid emission + normalize ----
    float bm[8];
    {
        int e5 = 1280 + xm * 5;
        unsigned e0 = TL[e5], e1 = TL[e5 + 1], e2 = TL[e5 + 2], e3 = TL[e5 + 3];
        pa[0] *= __uint_as_float(e0 << 16); pa[1] *= __uint_as_float(e0 & 0xffff0000u);
        pa[2] *= __uint_as_float(e1 << 16); pa[3] *= __uint_as_float(e1 & 0xffff0000u);
        pa[4] *= __uint_as_float(e2 << 16); pa[5] *= __uint_as_float(e2 & 0xffff0000u);
        pa[6] *= __uint_as_float(e3 << 16); pa[7] *= __uint_as_float(e3 & 0xffff0000u);
        float nu = ((pa[0] + pa[1]) + (pa[2] + pa[3])) + ((pa[4] + pa[5]) + (pa[6] + pa[7]));
        ll += __logf(nu);
        float rn = __builtin_amdgcn_rcpf(nu);
        #pragma unroll
        for (int c = 0; c < 8; ++c) bm[c] = pa[c] * rn;
    }

    // ---- level-4 root: butterfly over octet, stash in LDS ----
    {
        float pr[8] = {0.f, 0.f, 0.f, 0.f, 0.f, 0.f, 0.f, 0.f};
        const float4* mr = (const float4*)(MtN + (gu << 9) + (u << 6));
        #pragma unroll
        for (int j = 0; j < 8; ++j) {
            float4 m0 = mr[j * 2], m1 = mr[j * 2 + 1];
            float b = bm[j];
            pr[0] = fmaf(b, m0.x, pr[0]); pr[1] = fmaf(b, m0.y, pr[1]);
            pr[2] = fmaf(b, m0.z, pr[2]); pr[3] = fmaf(b, m0.w, pr[3]);
            pr[4] = fmaf(b, m1.x, pr[4]); pr[5] = fmaf(b, m1.y, pr[5]);
            pr[6] = fmaf(b, m1.z, pr[6]); pr[7] = fmaf(b, m1.w, pr[7]);
        }
        #pragma unroll
        for (int m = 1; m <= 4; m <<= 1) {
            #pragma unroll
            for (int i = 0; i < 8; ++i) pr[i] += __shfl_xor(pr[i], m);
        }
        int e5 = 1280 + xr * 5;
        unsigned e0 = TL[e5], e1 = TL[e5 + 1], e2 = TL[e5 + 2], e3 = TL[e5 + 3];
        pr[0] *= __uint_as_float(e0 << 16); pr[1] *= __uint_as_float(e0 & 0xffff0000u);
        pr[2] *= __uint_as_float(e1 << 16); pr[3] *= __uint_as_float(e1 & 0xffff0000u);
        pr[4] *= __uint_as_float(e2 << 16); pr[5] *= __uint_as_float(e2 & 0xffff0000u);
        pr[6] *= __uint_as_float(e3 << 16); pr[7] *= __uint_as_float(e3 & 0xffff0000u);
        float nur = ((pr[0] + pr[1]) + (pr[2] + pr[3])) + ((pr[4] + pr[5]) + (pr[6] + pr[7]));
        float rr = __builtin_amdgcn_rcpf(nur);
        if (u == 0) {
            ll += __logf(nur);
            float4* dp = (float4*)(b4 + (tid >> 3) * 8);
            dp[0] = make_float4(pr[0] * rr, pr[1] * rr, pr[2] * rr, pr[3] * rr);
            dp[1] = make_float4(pr[4] * rr, pr[5] * rr, pr[6] * rr, pr[7] * rr);
        }
    }
    __syncthreads();

    // ---- level 4 -> 3: 4 nodes, octet scheme on threads 0..31 ----
    if (tid < 32) {
        int p = tid >> 3, j = tid & 7;
        int s3 = pg * 4 + p;                 // global level-3 index 0..1023
        int t3 = (s3 >= 512) ? 1 : 0;
        int l3 = s3 - t3 * 512;
        float bch[8];
        #pragma unroll
        for (int l = 0; l < 8; ++l) bch[l] = b4[(p * 8 + l) * 8 + j];
        float pr[8] = {0.f, 0.f, 0.f, 0.f, 0.f, 0.f, 0.f, 0.f};
        #pragma unroll
        for (int l = 0; l < 8; ++l) {
            const float4* mp = (const float4*)(MtN + (gu << 9) + (l << 6) + (j << 3));
            float4 m0 = mp[0], m1 = mp[1];
            float b = bch[l];
            pr[0] = fmaf(b, m0.x, pr[0]); pr[1] = fmaf(b, m0.y, pr[1]);
            pr[2] = fmaf(b, m0.z, pr[2]); pr[3] = fmaf(b, m0.w, pr[3]);
            pr[4] = fmaf(b, m1.x, pr[4]); pr[5] = fmaf(b, m1.y, pr[5]);
            pr[6] = fmaf(b, m1.z, pr[6]); pr[7] = fmaf(b, m1.w, pr[7]);
        }
        #pragma unroll
        for (int m = 1; m <= 4; m <<= 1) {
            #pragma unroll
            for (int i = 0; i < 8; ++i) pr[i] += __shfl_xor(pr[i], m);
        }
        int x3 = x[t3 * NT_NODES + S3 + l3];
        int e5 = 1280 + x3 * 5;
        unsigned e0 = TL[e5], e1 = TL[e5 + 1], e2 = TL[e5 + 2], e3 = TL[e5 + 3];
        pr[0] *= __uint_as_float(e0 << 16); pr[1] *= __uint_as_float(e0 & 0xffff0000u);
        pr[2] *= __uint_as_float(e1 << 16); pr[3] *= __uint_as_float(e1 & 0xffff0000u);
        pr[4] *= __uint_as_float(e2 << 16); pr[5] *= __uint_as_float(e2 & 0xffff0000u);
        pr[6] *= __uint_as_float(e3 << 16); pr[7] *= __uint_as_float(e3 & 0xffff0000u);
        float nur = ((pr[0] + pr[1]) + (pr[2] + pr[3])) + ((pr[4] + pr[5]) + (pr[6] + pr[7]));
        float rr = __builtin_amdgcn_rcpf(nur);
        if (j == 0) {
            ll += __logf(nur);
            float4* dp = (float4*)(lv3 + ((size_t)g * 1024 + s3) * 8);
            dp[0] = make_float4(pr[0] * rr, pr[1] * rr, pr[2] * rr, pr[3] * rr);
            dp[1] = make_float4(pr[4] * rr, pr[5] * rr, pr[6] * rr, pr[7] * rr);
        }
    }

    // ---- block ll reduce -> llout[g][pg] (block is single-tree) ----
    #pragma unroll
    for (int m = 1; m < 64; m <<= 1) ll += __shfl_xor(ll, m);
    if (lane == 0) llp[wave] = ll;
    __syncthreads();
    if (tid == 0) llout[gu * 256 + pg] = (llp[0] + llp[1]) + (llp[2] + llp[3]);
}

// ---------------- uptop: one block per g — levels 3->2->1->0 + output ----------------
__global__ __launch_bounds__(256) void uptop(
    const float* __restrict__ MtN, const float* __restrict__ smBtN,
    const int* __restrict__ x,
    const float* __restrict__ lv3,   // [g][1024][8]
    const float* __restrict__ ll1,   // [g][256]
    float* __restrict__ out)         // [2][16]
{
    int g = blockIdx.x;   // 0..15
    int tid = threadIdx.x;
    __shared__ __align__(16) float bet2[128 * 8];
    __shared__ __align__(16) float bet1[16 * 8];
    __shared__ float redA[256], redB[256];

    float ll0 = 0.f, llt1 = 0.f;
    {
        float v = ll1[g * 256 + tid];
        if (tid < 128) ll0 = v; else llt1 = v;
    }

    const float* Mg = MtN + (g << 9);

    // ---- phase A: level 3 -> 2 (128 tasks, 1/thread) ----
    if (tid < 128) {
        int t = tid >> 6, n2 = tid & 63;
        float bch[64];
        const float4* sp = (const float4*)(lv3 + ((size_t)g * 1024 + t * 512 + n2 * 8) * 8);
        #pragma unroll
        for (int v = 0; v < 16; ++v) {
            float4 f = sp[v];
            bch[4 * v + 0] = f.x; bch[4 * v + 1] = f.y;
            bch[4 * v + 2] = f.z; bch[4 * v + 3] = f.w;
        }
        float pa[8] = {0.f, 0.f, 0.f, 0.f, 0.f, 0.f, 0.f, 0.f};
        #pragma unroll
        for (int k = 0; k < 64; ++k) {
            float b = bch[k];
            #pragma unroll
            for (int i = 0; i < 8; ++i) pa[i] = fmaf(b, Mg[k * 8 + i], pa[i]);
        }
        int x2 = x[t * NT_NODES + S2 + n2];
        const float4* ep = (const float4*)(smBtN + ((g << 5) + x2) * 8);
        float4 e0 = ep[0], e1 = ep[1];
        pa[0] *= e0.x; pa[1] *= e0.y; pa[2] *= e0.z; pa[3] *= e0.w;
        pa[4] *= e1.x; pa[5] *= e1.y; pa[6] *= e1.z; pa[7] *= e1.w;
        float nu = ((pa[0] + pa[1]) + (pa[2] + pa[3])) + ((pa[4] + pa[5]) + (pa[6] + pa[7]));
        float lg = __logf(nu);
        if (t == 0) ll0 += lg; else llt1 += lg;
        float rn = __builtin_amdgcn_rcpf(nu);
        float4* dp = (float4*)(bet2 + tid * 8);
        dp[0] = make_float4(pa[0] * rn, pa[1] * rn, pa[2] * rn, pa[3] * rn);
        dp[1] = make_float4(pa[4] * rn, pa[5] * rn, pa[6] * rn, pa[7] * rn);
    }
    __syncthreads();

    // ---- phase B: level 2 -> 1 (16 nodes, octet scheme on threads 0..127) ----
    if (tid < 128) {
        int o = tid >> 3, j = tid & 7;
        int t = o >> 3, n1 = o & 7;
        bool c0 = (j & 1) != 0, c1 = (j & 2) != 0, c2 = (j & 4) != 0;
        float bch[8];
        #pragma unroll
        for (int l = 0; l < 8; ++l) bch[l] = bet2[(t * 64 + n1 * 8 + l) * 8 + j];
        float pr[8] = {0.f, 0.f, 0.f, 0.f, 0.f, 0.f, 0.f, 0.f};
        #pragma unroll
        for (int l = 0; l < 8; ++l) {
            const float4* mp = (const float4*)(MtN + (g << 9) + (l << 6) + (j << 3));
            float4 m0 = mp[0], m1 = mp[1];
            float b = bch[l];
            pr[0] = fmaf(b, m0.x, pr[0]); pr[1] = fmaf(b, m0.y, pr[1]);
            pr[2] = fmaf(b, m0.z, pr[2]); pr[3] = fmaf(b, m0.w, pr[3]);
            pr[4] = fmaf(b, m1.x, pr[4]); pr[5] = fmaf(b, m1.y, pr[5]);
            pr[6] = fmaf(b, m1.z, pr[6]); pr[7] = fmaf(b, m1.w, pr[7]);
        }
        #pragma unroll
        for (int m = 1; m <= 4; m <<= 1) {
            #pragma unroll
            for (int i = 0; i < 8; ++i) pr[i] += __shfl_xor(pr[i], m);
        }
        int x1 = x[t * NT_NODES + S1 + n1];
        const float4* ep = (const float4*)(smBtN + ((g << 5) + x1) * 8);
        float4 e0 = ep[0], e1 = ep[1];
        pr[0] *= e0.x; pr[1] *= e0.y; pr[2] *= e0.z; pr[3] *= e0.w;
        pr[4] *= e1.x; pr[5] *= e1.y; pr[6] *= e1.z; pr[7] *= e1.w;
        float nu = ((pr[0] + pr[1]) + (pr[2] + pr[3])) + ((pr[4] + pr[5]) + (pr[6] + pr[7]));
        if (j == 0) { float lg = __logf(nu); if (t == 0) ll0 += lg; else llt1 += lg; }
        float rn = __builtin_amdgcn_rcpf(nu);
        bet1[o * 8 + j] = sel8(pr, c0, c1, c2) * rn;
    }
    __syncthreads();

    // ---- phase C: level 1 -> 0 (2 roots, octets on threads 0..15) ----
    if (tid < 16) {
        int t = tid >> 3, j = tid & 7;
        float bch[8];
        #pragma unroll
        for (int l = 0; l < 8; ++l) bch[l] = bet1[(t * 8 + l) * 8 + j];
        float pr[8] = {0.f, 0.f, 0.f, 0.f, 0.f, 0.f, 0.f, 0.f};
        #pragma unroll
        for (int l = 0; l < 8; ++l) {
            const float4* mp = (const float4*)(MtN + (g << 9) + (l << 6) + (j << 3));
            float4 m0 = mp[0], m1 = mp[1];
            float b = bch[l];
            pr[0] = fmaf(b, m0.x, pr[0]); pr[1] = fmaf(b, m0.y, pr[1]);
            pr[2] = fmaf(b, m0.z, pr[2]); pr[3] = fmaf(b, m0.w, pr[3]);
            pr[4] = fmaf(b, m1.x, pr[4]); pr[5] = fmaf(b, m1.y, pr[5]);
            pr[6] = fmaf(b, m1.z, pr[6]); pr[7] = fmaf(b, m1.w, pr[7]);
        }
        #pragma unroll
        for (int m = 1; m <= 4; m <<= 1) {
            #pragma unroll
            for (int i = 0; i < 8; ++i) pr[i] += __shfl_xor(pr[i], m);
        }
        int x0 = x[t * NT_NODES + S0];
        const float4* ep = (const float4*)(smBtN + ((g << 5) + x0) * 8);
        float4 e0 = ep[0], e1 = ep[1];
        pr[0] *= e0.x; pr[1] *= e0.y; pr[2] *= e0.z; pr[3] *= e0.w;
        pr[4] *= e1.x; pr[5] *= e1.y; pr[6] *= e1.z; pr[7] *= e1.w;
        float nu = ((pr[0] + pr[1]) + (pr[2] + pr[3])) + ((pr[4] + pr[5]) + (pr[6] + pr[7]));
        if (j == 0) { float lg = __logf(nu); if (t == 0) ll0 += lg; else llt1 += lg; }
    }

    // ---- deterministic block reduction -> out[2][16] ----
    redA[tid] = ll0; redB[tid] = llt1;
    __syncthreads();
    for (int step = 128; step > 0; step >>= 1) {
        if (tid < step) { redA[tid] += redA[tid + step]; redB[tid] += redB[tid + step]; }
        __syncthreads();
    }
    if (tid == 0) { out[g] = redA[0]; out[16 + g] = redB[0]; }
}

extern "C" void kernel_launch(void* const* d_in, const int* in_sizes, int n_in,
                              void* d_out, int out_size, void* d_ws, size_t ws_size,
                              hipStream_t stream)
{
    const float* A  = (const float*)d_in[0];
    const float* B  = (const float*)d_in[1];
    const float* Pi = (const float*)d_in[2];
    const float* SP = (const float*)d_in[3];
    const int*   x  = (const int*)d_in[4];

    float* ws     = (float*)d_ws;
    float* MtN    = ws;                       // 8192
    float* smBtN  = MtN + 8192;               // 4096
    unsigned* Tp  = (unsigned*)(smBtN + 4096); // 16*5*256 = 20480
    unsigned* EMp = Tp + 20480;               // 16*4*32 = 2048
    float* lv3    = (float*)(EMp + 2048);     // 16*1024*8 = 131072
    float* ll1    = lv3 + 131072;             // 16*256 = 4096
    float* out    = (float*)d_out;

    stage0T<<<16, 256, 0, stream>>>(A, B, Pi, SP, MtN, smBtN, Tp, EMp);
    // levels 6 -> 5 -> 4 -> 3
    upleaf<<<4096, 256, 0, stream>>>(MtN, Tp, EMp, x, lv3, ll1);
    // levels 3 -> 2 -> 1 -> 0 (+ fold ll1), writes out[2][16]
    uptop<<<16, 256, 0, stream>>>(MtN, smBtN, x, lv3, ll1, out);
}